// Round 10
// baseline (190.404 us; speedup 1.0000x reference)
//
#include <hip/hip_runtime.h>

#define HDIM 20
#define BLOCK 256

typedef __fp16 half8 __attribute__((ext_vector_type(8)));
typedef __fp16 half2v __attribute__((ext_vector_type(2)));
typedef float  float4v __attribute__((ext_vector_type(4)));
typedef int    int4v  __attribute__((ext_vector_type(4)));

static __device__ __forceinline__ float4v mfma16(half8 a, half8 b, float4v c) {
    return __builtin_amdgcn_mfma_f32_16x16x32_f16(a, b, c, 0, 0, 0);
}

// KEY INVARIANT (no cross-lane traffic in the 200-step loop):
//   B-row permutation: k = 8q + i <-> hidden unit 4i + q (i<5; i=5,6 pad; k=7(q=0) bias=1).
//   C/D layout (m89): lane (q,el) holds D rows 4q..4q+3 of column el.
//   A tile T, row 4q'+g = unit 4T+q', gate g in {r,z,nI,nH} -> lane (q,el)
//   computes h_new for units {4T+q} = exactly its own B rows k=8q+T.
// Round 10 (= round 9 resubmit; infra failure last round): transcendental
// issue (~16 cyc/op wave64) is 76% of the issue-bound loop. r and n sigmoids
// -> 512-interval lerp LUT in LDS (DS pipe idle); z stays on exp2+rcp to
// balance the per-CU LDS pipe. LUT input transform folded into A: r-rows
// scaled x32, nI/nH x64 (tanh(x)=2*sigma(2x)-1), z-rows x(-log2e).

__global__ __launch_bounds__(BLOCK, 2) void gru_decoder_kernel(
    const float* __restrict__ hidden,
    const float* __restrict__ w_ih,
    const float* __restrict__ w_hh,
    const float* __restrict__ b_ih,
    const float* __restrict__ b_hh,
    const float* __restrict__ w_l,
    const float* __restrict__ b_l,
    const int*  __restrict__ step_ptr,
    float* __restrict__ out,
    int B)
{
    __shared__ unsigned tab[512];   // half2 {sigma(x0), sigma(x0+1/32)-sigma(x0)}, x0=(i-256)/32

    const int tid = threadIdx.x;
    // ---- build sigmoid LUT (once per block) ----
    const float L2E = 1.4426950408889634f;
    for (int i = tid; i < 512; i += BLOCK) {
        float x0 = (float)(i - 256) * (1.0f / 32.0f);
        float x1 = x0 + 1.0f / 32.0f;
        float y0 = 1.0f / (1.0f + __builtin_amdgcn_exp2f(-x0 * L2E));
        float y1 = 1.0f / (1.0f + __builtin_amdgcn_exp2f(-x1 * L2E));
        half2v bs; bs[0] = (__fp16)y0; bs[1] = (__fp16)(y1 - y0);
        tab[i] = __builtin_bit_cast(unsigned, bs);
    }
    __syncthreads();

    const int l   = tid & 63;
    const int wv  = tid >> 6;
    const int el  = l & 15;
    const int q   = l >> 4;
    const int e   = (blockIdx.x * 4 + wv) * 16 + el;
    const int step = *step_ptr;

    const float NL2E = -1.4426950408889634f;   // z scale (exp2 path)
    const float SR   = 32.0f;                  // r scale (LUT coord, 1/32 interval)
    const float SN   = 64.0f;                  // n scale (sigma(2x) -> 2*32)

    // ---- A fragments (once). Lane holds k=8q..8q+7; A row m=el of tile T is
    // unit 4T+(el>>2), gate type el&3 {0:r,1:z,2:nI,3:nH}. ----
    const int u_dst = el >> 2;
    const int g     = el & 3;

    half8 Afold[5], Azero[5], Ay;
    #pragma unroll
    for (int T = 0; T < 5; ++T) {
        const int u  = 4 * T + u_dst;
        const int rr = (g == 0) ? u : (g == 1) ? 20 + u : 40 + u;
        const float sc = (g == 0) ? SR : (g == 1) ? NL2E : SN;
        half8 hf, h0;
        #pragma unroll
        for (int j = 0; j < 8; ++j) {
            float af = 0.f, a0 = 0.f;
            if (j < 5) {
                const int uk = 4 * j + q;
                float wx = w_ih[rr * 2 + 0] * w_l[uk] + w_ih[rr * 2 + 1] * w_l[HDIM + uk];
                float wh = w_hh[rr * HDIM + uk];
                if (g <= 1)      { af = wh + wx; a0 = wh; }
                else if (g == 2) { af = wx;      a0 = 0.f; }
                else             { af = wh;      a0 = wh; }
            } else if (j == 7 && q == 0) {
                float bx = w_ih[rr * 2 + 0] * b_l[0] + w_ih[rr * 2 + 1] * b_l[1];
                if (g <= 1)      { af = b_ih[rr] + b_hh[rr] + bx; a0 = b_ih[rr] + b_hh[rr]; }
                else if (g == 2) { af = b_ih[rr] + bx;            a0 = b_ih[rr]; }
                else             { af = b_hh[rr];                 a0 = b_hh[rr]; }
            }
            hf[j] = (__fp16)(af * sc);
            h0[j] = (__fp16)(a0 * sc);
        }
        Afold[T] = hf;
        Azero[T] = h0;
    }
    {   // y tile (unscaled)
        half8 hy;
        #pragma unroll
        for (int j = 0; j < 8; ++j) {
            float v = 0.f;
            if (el < 2) {
                if (j < 5)                 v = w_l[el * HDIM + 4 * j + q];
                else if (j == 7 && q == 0) v = b_l[el];
            }
            hy[j] = (__fp16)v;
        }
        Ay = hy;
    }

    int w3const;
    {
        half2v c67; c67[0] = (__fp16)0.f; c67[1] = (__fp16)((q == 0) ? 1.f : 0.f);
        w3const = __builtin_bit_cast(int, c67);
    }

    // ---- state ----
    float hprev[5];
    half8 Bf;
    {
        const float* hb = hidden + (size_t)e * HDIM;
        #pragma unroll
        for (int T = 0; T < 5; ++T) hprev[T] = hb[4 * T + q];
        int4v bi;
        bi[0] = __builtin_bit_cast(int, __builtin_amdgcn_cvt_pkrtz(hprev[0], hprev[1]));
        bi[1] = __builtin_bit_cast(int, __builtin_amdgcn_cvt_pkrtz(hprev[2], hprev[3]));
        bi[2] = __builtin_bit_cast(int, __builtin_amdgcn_cvt_pkrtz(hprev[4], 0.f));
        bi[3] = w3const;
        Bf = __builtin_bit_cast(half8, bi);
    }

    const float4v czero = {0.f, 0.f, 0.f, 0.f};

    // sigma(x) where t = x*32 (pre-scaled in A): lerp LUT, ~8 full-rate ops
    auto lut = [&](float t) -> float {
        float u = t + 256.f;
        u = __builtin_amdgcn_fmed3f(u, 0.f, 511.9995f);
        int i = (int)u;                               // trunc == floor (u>=0)
        float f = __builtin_amdgcn_fractf(u);
        half2v bs = __builtin_bit_cast(half2v, tab[i]);
        return __builtin_fmaf(f, (float)bs[1], (float)bs[0]);
    };

    auto do_step = [&](const half8* A) {
        float4v C[5];
        #pragma unroll
        for (int T = 0; T < 5; ++T) C[T] = mfma16(A[T], Bf, czero);
        #pragma unroll
        for (int T = 0; T < 5; ++T) {
            // C = (32*ar, -log2e*az, 64*anI, 64*anH)
            float r = lut(C[T][0]);
            float ez = __builtin_amdgcn_exp2f(C[T][1]);
            float z = __builtin_amdgcn_rcpf(1.f + ez);
            float tn = __builtin_fmaf(r, C[T][3], C[T][2]);   // 64*npre
            float sn = lut(tn);
            float n = __builtin_fmaf(2.f, sn, -1.f);          // tanh
            hprev[T] = __builtin_fmaf(z, hprev[T] - n, n);    // (1-z)*n + z*h
        }
        int4v bi;
        bi[0] = __builtin_bit_cast(int, __builtin_amdgcn_cvt_pkrtz(hprev[0], hprev[1]));
        bi[1] = __builtin_bit_cast(int, __builtin_amdgcn_cvt_pkrtz(hprev[2], hprev[3]));
        bi[2] = __builtin_bit_cast(int, __builtin_amdgcn_cvt_pkrtz(hprev[4], 0.f));
        bi[3] = w3const;
        Bf = __builtin_bit_cast(half8, bi);
    };

    float* outp = out + (size_t)e * 2 * step;

    do_step(Azero);                                   // h_0 -> h_1  (x=0 step)
    for (int t = 1; t < step; ++t) {
        float4v cy = mfma16(Ay, Bf, czero);           // y_{t-1} = w_l . h_t + b_l
        if (q == 0) {
            float2 st; st.x = cy[0]; st.y = cy[1];
            *(float2*)(outp + 2 * (step - t)) = st;   // reversed time index
        }
        do_step(Afold);                               // h_t -> h_{t+1} (x folded)
    }
    {   // final y_{step-1}
        float4v cy = mfma16(Ay, Bf, czero);
        if (q == 0) {
            float2 st; st.x = cy[0]; st.y = cy[1];
            *(float2*)(outp + 0) = st;
        }
    }
}

extern "C" void kernel_launch(void* const* d_in, const int* in_sizes, int n_in,
                              void* d_out, int out_size, void* d_ws, size_t ws_size,
                              hipStream_t stream) {
    const float* hidden = (const float*)d_in[0];
    const float* w_ih   = (const float*)d_in[1];
    const float* w_hh   = (const float*)d_in[2];
    const float* b_ih   = (const float*)d_in[3];
    const float* b_hh   = (const float*)d_in[4];
    const float* w_l    = (const float*)d_in[5];
    const float* b_l    = (const float*)d_in[6];
    const int*   step   = (const int*)d_in[7];
    float* out = (float*)d_out;

    int B = in_sizes[0] / HDIM;     // hidden is (1, B, 20); B = 32768
    int grid = B / 64;              // 4 waves/block x 16 elements/wave

    gru_decoder_kernel<<<grid, BLOCK, 0, stream>>>(
        hidden, w_ih, w_hh, b_ih, b_hh, w_l, b_l, step, out, B);
}

// Round 11
// 169.422 us; speedup vs baseline: 1.1238x; 1.1238x over previous
//
#include <hip/hip_runtime.h>

#define HDIM 20
#define BLOCK 256

typedef __fp16 half8 __attribute__((ext_vector_type(8)));
typedef __fp16 half2v __attribute__((ext_vector_type(2)));
typedef float  float4v __attribute__((ext_vector_type(4)));
typedef int    int4v  __attribute__((ext_vector_type(4)));

static __device__ __forceinline__ float4v mfma16(half8 a, half8 b, float4v c) {
    return __builtin_amdgcn_mfma_f32_16x16x32_f16(a, b, c, 0, 0, 0);
}

// KEY INVARIANT (no cross-lane traffic in the 200-step loop):
//   B-row permutation: k = 8q + i <-> hidden unit 4i + q (i<5; i=5,6 pad; k=7(q=0) bias=1).
//   C/D layout (m89): lane (q,el) holds D rows 4q..4q+3 of column el.
//   A tile T, row 4q'+g = unit 4T+q', gate g in {r,z,nI,nH} -> lane (q,el)
//   computes h_new for units {4T+q} = exactly its own B rows k=8q+T.
// Round 11: revert R10's LUT (regressed: DS latency on critical chain, no
// issue savings). R7 structure + convoy-softening: 6 MFMAs (gates+y, same Bf)
// issued together; y-store delayed one iteration into the next step's
// MFMA-latency shadow; decrementing store pointer; unroll 2.
// A rows pre-scaled: r,z by -log2e ; nI,nH by +2log2e.

__global__ __launch_bounds__(BLOCK, 2) void gru_decoder_kernel(
    const float* __restrict__ hidden,
    const float* __restrict__ w_ih,
    const float* __restrict__ w_hh,
    const float* __restrict__ b_ih,
    const float* __restrict__ b_hh,
    const float* __restrict__ w_l,
    const float* __restrict__ b_l,
    const int*  __restrict__ step_ptr,
    float* __restrict__ out,
    int B)
{
    const int tid = threadIdx.x;
    const int l   = tid & 63;
    const int wv  = tid >> 6;
    const int el  = l & 15;
    const int q   = l >> 4;
    const int e   = (blockIdx.x * 4 + wv) * 16 + el;
    const int step = *step_ptr;

    const float NL2E  = -1.4426950408889634f;   // r,z scale
    const float T2L2E =  2.8853900817779268f;   // n scale

    // ---- A fragments (once). Lane holds k=8q..8q+7; A row m=el of tile T is
    // unit 4T+(el>>2), gate type el&3 {0:r,1:z,2:nI,3:nH}. ----
    const int u_dst = el >> 2;
    const int g     = el & 3;

    half8 Afold[5], Azero[5], Ay;
    #pragma unroll
    for (int T = 0; T < 5; ++T) {
        const int u  = 4 * T + u_dst;
        const int rr = (g == 0) ? u : (g == 1) ? 20 + u : 40 + u;
        const float sc = (g <= 1) ? NL2E : T2L2E;
        half8 hf, h0;
        #pragma unroll
        for (int j = 0; j < 8; ++j) {
            float af = 0.f, a0 = 0.f;
            if (j < 5) {
                const int uk = 4 * j + q;
                float wx = w_ih[rr * 2 + 0] * w_l[uk] + w_ih[rr * 2 + 1] * w_l[HDIM + uk];
                float wh = w_hh[rr * HDIM + uk];
                if (g <= 1)      { af = wh + wx; a0 = wh; }
                else if (g == 2) { af = wx;      a0 = 0.f; }
                else             { af = wh;      a0 = wh; }
            } else if (j == 7 && q == 0) {
                float bx = w_ih[rr * 2 + 0] * b_l[0] + w_ih[rr * 2 + 1] * b_l[1];
                if (g <= 1)      { af = b_ih[rr] + b_hh[rr] + bx; a0 = b_ih[rr] + b_hh[rr]; }
                else if (g == 2) { af = b_ih[rr] + bx;            a0 = b_ih[rr]; }
                else             { af = b_hh[rr];                 a0 = b_hh[rr]; }
            }
            hf[j] = (__fp16)(af * sc);
            h0[j] = (__fp16)(a0 * sc);
        }
        Afold[T] = hf;
        Azero[T] = h0;
    }
    {   // y tile (unscaled): row 0 = w_l row 0, row 1 = w_l row 1, bias at k=7
        half8 hy;
        #pragma unroll
        for (int j = 0; j < 8; ++j) {
            float v = 0.f;
            if (el < 2) {
                if (j < 5)                 v = w_l[el * HDIM + 4 * j + q];
                else if (j == 7 && q == 0) v = b_l[el];
            }
            hy[j] = (__fp16)v;
        }
        Ay = hy;
    }

    int w3const;
    {
        half2v c67; c67[0] = (__fp16)0.f; c67[1] = (__fp16)((q == 0) ? 1.f : 0.f);
        w3const = __builtin_bit_cast(int, c67);
    }

    // ---- state ----
    float hprev[5];
    half8 Bf;
    {
        const float* hb = hidden + (size_t)e * HDIM;
        #pragma unroll
        for (int T = 0; T < 5; ++T) hprev[T] = hb[4 * T + q];
        int4v bi;
        bi[0] = __builtin_bit_cast(int, __builtin_amdgcn_cvt_pkrtz(hprev[0], hprev[1]));
        bi[1] = __builtin_bit_cast(int, __builtin_amdgcn_cvt_pkrtz(hprev[2], hprev[3]));
        bi[2] = __builtin_bit_cast(int, __builtin_amdgcn_cvt_pkrtz(hprev[4], 0.f));
        bi[3] = w3const;
        Bf = __builtin_bit_cast(half8, bi);
    }

    const float4v czero = {0.f, 0.f, 0.f, 0.f};

    auto elementwise = [&](const float4v* C) {
        #pragma unroll
        for (int T = 0; T < 5; ++T) {
            // C = (-log2e*ar, -log2e*az, 2log2e*anI, 2log2e*anH)
            float r = __builtin_amdgcn_rcpf(1.f + __builtin_amdgcn_exp2f(C[T][0]));
            float z = __builtin_amdgcn_rcpf(1.f + __builtin_amdgcn_exp2f(C[T][1]));
            float npre2 = __builtin_fmaf(r, C[T][3], C[T][2]);
            float tn = __builtin_amdgcn_rcpf(1.f + __builtin_amdgcn_exp2f(npre2));
            float n = __builtin_fmaf(-2.f, tn, 1.f);
            hprev[T] = __builtin_fmaf(z, hprev[T] - n, n);   // (1-z)*n + z*h
        }
        int4v bi;
        bi[0] = __builtin_bit_cast(int, __builtin_amdgcn_cvt_pkrtz(hprev[0], hprev[1]));
        bi[1] = __builtin_bit_cast(int, __builtin_amdgcn_cvt_pkrtz(hprev[2], hprev[3]));
        bi[2] = __builtin_bit_cast(int, __builtin_amdgcn_cvt_pkrtz(hprev[4], 0.f));
        bi[3] = w3const;
        Bf = __builtin_bit_cast(half8, bi);
    };

    float* outp = out + (size_t)e * 2 * step;

    // ---- step 0 (x = 0): h_0 -> h_1, no y yet ----
    {
        float4v C[5];
        #pragma unroll
        for (int T = 0; T < 5; ++T) C[T] = mfma16(Azero[T], Bf, czero);
        elementwise(C);
    }

    // ---- iteration t=1 peeled (no pending store) ----
    float2 cyP;
    {
        float4v C[5];
        #pragma unroll
        for (int T = 0; T < 5; ++T) C[T] = mfma16(Afold[T], Bf, czero);
        float4v cy = mfma16(Ay, Bf, czero);            // y_0 = w_l . h_1 + b_l
        cyP.x = cy[0]; cyP.y = cy[1];
        elementwise(C);                                 // h_1 -> h_2
    }

    // ---- main loop t = 2 .. step-1: store of y_{t-2} rides the MFMA shadow ----
    float* sp = outp + 2 * (step - 1);                  // y_0 goes here (reversed)
    #pragma unroll 2
    for (int t = 2; t < step; ++t) {
        float4v C[5];
        #pragma unroll
        for (int T = 0; T < 5; ++T) C[T] = mfma16(Afold[T], Bf, czero);
        float4v cy = mfma16(Ay, Bf, czero);            // y_{t-1} = w_l . h_t + b_l
        if (q == 0) *(float2*)sp = cyP;                // store y_{t-2} under MFMA latency
        sp -= 2;
        elementwise(C);                                 // h_t -> h_{t+1}
        cyP.x = cy[0]; cyP.y = cy[1];
    }

    // ---- tail: pending y_{step-2} at index 1, final y_{step-1} at index 0 ----
    {
        float4v cy = mfma16(Ay, Bf, czero);            // y_{step-1} = w_l . h_step + b_l
        if (q == 0) {
            *(float2*)(outp + 2) = cyP;
            float2 st; st.x = cy[0]; st.y = cy[1];
            *(float2*)(outp + 0) = st;
        }
    }
}

extern "C" void kernel_launch(void* const* d_in, const int* in_sizes, int n_in,
                              void* d_out, int out_size, void* d_ws, size_t ws_size,
                              hipStream_t stream) {
    const float* hidden = (const float*)d_in[0];
    const float* w_ih   = (const float*)d_in[1];
    const float* w_hh   = (const float*)d_in[2];
    const float* b_ih   = (const float*)d_in[3];
    const float* b_hh   = (const float*)d_in[4];
    const float* w_l    = (const float*)d_in[5];
    const float* b_l    = (const float*)d_in[6];
    const int*   step   = (const int*)d_in[7];
    float* out = (float*)d_out;

    int B = in_sizes[0] / HDIM;     // hidden is (1, B, 20); B = 32768
    int grid = B / 64;              // 4 waves/block x 16 elements/wave

    gru_decoder_kernel<<<grid, BLOCK, 0, stream>>>(
        hidden, w_ih, w_hh, b_ih, b_hh, w_l, b_l, step, out, B);
}

// Round 12
// 168.941 us; speedup vs baseline: 1.1270x; 1.0028x over previous
//
#include <hip/hip_runtime.h>

#define HDIM 20
#define BLOCK 256

typedef __fp16 half8 __attribute__((ext_vector_type(8)));
typedef __fp16 half2v __attribute__((ext_vector_type(2)));
typedef float  float4v __attribute__((ext_vector_type(4)));
typedef int    int4v  __attribute__((ext_vector_type(4)));

static __device__ __forceinline__ float4v mfma16(half8 a, half8 b, float4v c) {
    return __builtin_amdgcn_mfma_f32_16x16x32_f16(a, b, c, 0, 0, 0);
}

// KEY INVARIANT (no cross-lane traffic in the 200-step loop):
//   B-row permutation: k = 8q + i <-> hidden unit 4i + q (i<5; i=5,6 pad; k=7(q=0) bias=1).
//   C/D layout (m89): lane (q,el) holds D rows 4q..4q+3 of column el.
//   A tile T, row 4q'+g = unit 4T+q', gate g in {r,z,nI,nH} -> lane (q,el)
//   computes h_new for units {4T+q} = exactly its own B rows k=8q+T.
// Round 12: R11 + wave-pair de-phasing. The 2 co-resident waves/SIMD are
// symmetric and phase-lock (convoy): both hit MFMA-wait together, both burst
// transcendentals together -> 35% SIMD idle. One-time s_sleep(~640cyc = half
// a step) for the second half of the block range (blocks i and i+256 pair on
// a CU under round-robin dispatch) staggers the pair; no in-loop barriers
// exist to re-lock them. Timing hint only — correctness unaffected.
// A rows pre-scaled: r,z by -log2e ; nI,nH by +2log2e.

__global__ __launch_bounds__(BLOCK, 2) void gru_decoder_kernel(
    const float* __restrict__ hidden,
    const float* __restrict__ w_ih,
    const float* __restrict__ w_hh,
    const float* __restrict__ b_ih,
    const float* __restrict__ b_hh,
    const float* __restrict__ w_l,
    const float* __restrict__ b_l,
    const int*  __restrict__ step_ptr,
    float* __restrict__ out,
    int B)
{
    const int tid = threadIdx.x;
    const int l   = tid & 63;
    const int wv  = tid >> 6;
    const int el  = l & 15;
    const int q   = l >> 4;
    const int e   = (blockIdx.x * 4 + wv) * 16 + el;
    const int step = *step_ptr;

    const float NL2E  = -1.4426950408889634f;   // r,z scale
    const float T2L2E =  2.8853900817779268f;   // n scale

    // ---- A fragments (once). Lane holds k=8q..8q+7; A row m=el of tile T is
    // unit 4T+(el>>2), gate type el&3 {0:r,1:z,2:nI,3:nH}. ----
    const int u_dst = el >> 2;
    const int g     = el & 3;

    half8 Afold[5], Azero[5], Ay;
    #pragma unroll
    for (int T = 0; T < 5; ++T) {
        const int u  = 4 * T + u_dst;
        const int rr = (g == 0) ? u : (g == 1) ? 20 + u : 40 + u;
        const float sc = (g <= 1) ? NL2E : T2L2E;
        half8 hf, h0;
        #pragma unroll
        for (int j = 0; j < 8; ++j) {
            float af = 0.f, a0 = 0.f;
            if (j < 5) {
                const int uk = 4 * j + q;
                float wx = w_ih[rr * 2 + 0] * w_l[uk] + w_ih[rr * 2 + 1] * w_l[HDIM + uk];
                float wh = w_hh[rr * HDIM + uk];
                if (g <= 1)      { af = wh + wx; a0 = wh; }
                else if (g == 2) { af = wx;      a0 = 0.f; }
                else             { af = wh;      a0 = wh; }
            } else if (j == 7 && q == 0) {
                float bx = w_ih[rr * 2 + 0] * b_l[0] + w_ih[rr * 2 + 1] * b_l[1];
                if (g <= 1)      { af = b_ih[rr] + b_hh[rr] + bx; a0 = b_ih[rr] + b_hh[rr]; }
                else if (g == 2) { af = b_ih[rr] + bx;            a0 = b_ih[rr]; }
                else             { af = b_hh[rr];                 a0 = b_hh[rr]; }
            }
            hf[j] = (__fp16)(af * sc);
            h0[j] = (__fp16)(a0 * sc);
        }
        Afold[T] = hf;
        Azero[T] = h0;
    }
    {   // y tile (unscaled): row 0 = w_l row 0, row 1 = w_l row 1, bias at k=7
        half8 hy;
        #pragma unroll
        for (int j = 0; j < 8; ++j) {
            float v = 0.f;
            if (el < 2) {
                if (j < 5)                 v = w_l[el * HDIM + 4 * j + q];
                else if (j == 7 && q == 0) v = b_l[el];
            }
            hy[j] = (__fp16)v;
        }
        Ay = hy;
    }

    int w3const;
    {
        half2v c67; c67[0] = (__fp16)0.f; c67[1] = (__fp16)((q == 0) ? 1.f : 0.f);
        w3const = __builtin_bit_cast(int, c67);
    }

    // ---- state ----
    float hprev[5];
    half8 Bf;
    {
        const float* hb = hidden + (size_t)e * HDIM;
        #pragma unroll
        for (int T = 0; T < 5; ++T) hprev[T] = hb[4 * T + q];
        int4v bi;
        bi[0] = __builtin_bit_cast(int, __builtin_amdgcn_cvt_pkrtz(hprev[0], hprev[1]));
        bi[1] = __builtin_bit_cast(int, __builtin_amdgcn_cvt_pkrtz(hprev[2], hprev[3]));
        bi[2] = __builtin_bit_cast(int, __builtin_amdgcn_cvt_pkrtz(hprev[4], 0.f));
        bi[3] = w3const;
        Bf = __builtin_bit_cast(half8, bi);
    }

    // ---- de-phase: stagger the co-resident wave pair by ~half a step ----
    if ((blockIdx.x >> 8) & 1) __builtin_amdgcn_s_sleep(10);   // ~640 cyc

    const float4v czero = {0.f, 0.f, 0.f, 0.f};

    auto elementwise = [&](const float4v* C) {
        #pragma unroll
        for (int T = 0; T < 5; ++T) {
            // C = (-log2e*ar, -log2e*az, 2log2e*anI, 2log2e*anH)
            float r = __builtin_amdgcn_rcpf(1.f + __builtin_amdgcn_exp2f(C[T][0]));
            float z = __builtin_amdgcn_rcpf(1.f + __builtin_amdgcn_exp2f(C[T][1]));
            float npre2 = __builtin_fmaf(r, C[T][3], C[T][2]);
            float tn = __builtin_amdgcn_rcpf(1.f + __builtin_amdgcn_exp2f(npre2));
            float n = __builtin_fmaf(-2.f, tn, 1.f);
            hprev[T] = __builtin_fmaf(z, hprev[T] - n, n);   // (1-z)*n + z*h
        }
        int4v bi;
        bi[0] = __builtin_bit_cast(int, __builtin_amdgcn_cvt_pkrtz(hprev[0], hprev[1]));
        bi[1] = __builtin_bit_cast(int, __builtin_amdgcn_cvt_pkrtz(hprev[2], hprev[3]));
        bi[2] = __builtin_bit_cast(int, __builtin_amdgcn_cvt_pkrtz(hprev[4], 0.f));
        bi[3] = w3const;
        Bf = __builtin_bit_cast(half8, bi);
    };

    float* outp = out + (size_t)e * 2 * step;

    // ---- step 0 (x = 0): h_0 -> h_1, no y yet ----
    {
        float4v C[5];
        #pragma unroll
        for (int T = 0; T < 5; ++T) C[T] = mfma16(Azero[T], Bf, czero);
        elementwise(C);
    }

    // ---- iteration t=1 peeled (no pending store) ----
    float2 cyP;
    {
        float4v C[5];
        #pragma unroll
        for (int T = 0; T < 5; ++T) C[T] = mfma16(Afold[T], Bf, czero);
        float4v cy = mfma16(Ay, Bf, czero);            // y_0 = w_l . h_1 + b_l
        cyP.x = cy[0]; cyP.y = cy[1];
        elementwise(C);                                 // h_1 -> h_2
    }

    // ---- main loop t = 2 .. step-1: store of y_{t-2} rides the MFMA shadow ----
    float* sp = outp + 2 * (step - 1);                  // y_0 goes here (reversed)
    #pragma unroll 2
    for (int t = 2; t < step; ++t) {
        float4v C[5];
        #pragma unroll
        for (int T = 0; T < 5; ++T) C[T] = mfma16(Afold[T], Bf, czero);
        float4v cy = mfma16(Ay, Bf, czero);            // y_{t-1} = w_l . h_t + b_l
        if (q == 0) *(float2*)sp = cyP;                // store y_{t-2} under MFMA latency
        sp -= 2;
        elementwise(C);                                 // h_t -> h_{t+1}
        cyP.x = cy[0]; cyP.y = cy[1];
    }

    // ---- tail: pending y_{step-2} at index 1, final y_{step-1} at index 0 ----
    {
        float4v cy = mfma16(Ay, Bf, czero);            // y_{step-1} = w_l . h_step + b_l
        if (q == 0) {
            *(float2*)(outp + 2) = cyP;
            float2 st; st.x = cy[0]; st.y = cy[1];
            *(float2*)(outp + 0) = st;
        }
    }
}

extern "C" void kernel_launch(void* const* d_in, const int* in_sizes, int n_in,
                              void* d_out, int out_size, void* d_ws, size_t ws_size,
                              hipStream_t stream) {
    const float* hidden = (const float*)d_in[0];
    const float* w_ih   = (const float*)d_in[1];
    const float* w_hh   = (const float*)d_in[2];
    const float* b_ih   = (const float*)d_in[3];
    const float* b_hh   = (const float*)d_in[4];
    const float* w_l    = (const float*)d_in[5];
    const float* b_l    = (const float*)d_in[6];
    const int*   step   = (const int*)d_in[7];
    float* out = (float*)d_out;

    int B = in_sizes[0] / HDIM;     // hidden is (1, B, 20); B = 32768
    int grid = B / 64;              // 4 waves/block x 16 elements/wave

    gru_decoder_kernel<<<grid, BLOCK, 0, stream>>>(
        hidden, w_ih, w_hh, b_ih, b_hh, w_l, b_l, step, out, B);
}